// Round 8
// baseline (241.865 us; speedup 1.0000x reference)
//
#include <hip/hip_runtime.h>
#include <hip/hip_fp16.h>
#include <math.h>

#define DIM      64
#define N_MEM    32
#define N_ENTITY 500000
#define N_REL    32
#define N_ITEM   10000
#define HOPS     2
#define BATCH    4096
#define HIST     50

typedef float4 f4;

__device__ __forceinline__ void unpack8(const uint4& r, float f[8]) {
    union { unsigned int u; __half2 h; } c;
    c.u = r.x; f[0] = __low2float(c.h); f[1] = __high2float(c.h);
    c.u = r.y; f[2] = __low2float(c.h); f[3] = __high2float(c.h);
    c.u = r.z; f[4] = __low2float(c.h); f[5] = __high2float(c.h);
    c.u = r.w; f[6] = __low2float(c.h); f[7] = __high2float(c.h);
}

// ---------------------------------------------------------------------------
// Pass 0: stream entity table -> fp16 copy (row = 128B = ONE cache line),
// plus rdot[r] = dot(relation[r], w_r). Leaves fp16 table L3-resident.
// ---------------------------------------------------------------------------
__global__ __launch_bounds__(256) void ripple_convert(
    const float* __restrict__ entity_emb,
    const float* __restrict__ relation_emb,
    const float* __restrict__ W_w,
    unsigned int* __restrict__ eh,      // [N_ENTITY][32] uints (64 fp16/row)
    float* __restrict__ rdot)           // [N_REL]
{
    const int wave = (blockIdx.x * blockDim.x + threadIdx.x) >> 6;
    const int lane = threadIdx.x & 63;
    const int g = lane >> 4;
    const int p = lane & 15;
    const int row = wave * 4 + g;
    if (row < N_ENTITY) {
        const f4 e4 = ((const f4*)entity_emb)[(size_t)row * 16 + p];
        const __half2 lo = __floats2half2_rn(e4.x, e4.y);
        const __half2 hi = __floats2half2_rn(e4.z, e4.w);
        uint2 pk;
        pk.x = *(const unsigned int*)&lo;
        pk.y = *(const unsigned int*)&hi;
        ((uint2*)eh)[(size_t)row * 16 + p] = pk;
    } else if (row < N_ENTITY + N_REL) {
        const int r = row - N_ENTITY;
        const f4 wr = ((const f4*)W_w)[16 + p];
        const f4 r4 = ((const f4*)relation_emb)[(size_t)r * 16 + p];
        float vr = r4.x * wr.x + r4.y * wr.y + r4.z * wr.z + r4.w * wr.w;
        vr += __shfl_xor(vr, 1, 64);
        vr += __shfl_xor(vr, 2, 64);
        vr += __shfl_xor(vr, 4, 64);
        vr += __shfl_xor(vr, 8, 64);
        if (p == 0) rdot[r] = vr;
    }
}

// ---------------------------------------------------------------------------
// Stage 1: one wave per (item, hop). fp16 rows, 8 lanes/row, uint4/lane:
// one gather instruction = 8 rows, ONE 128B line-request per row.
// 8 gather instrs/wave total (4 head + 4 tail) vs 24 (and 192 line-reqs) in R5.
// ---------------------------------------------------------------------------
__global__ __launch_bounds__(256) void ripple_stage1(
    const float* __restrict__ W_w,
    const float* __restrict__ W_b,
    const int*   __restrict__ heads,
    const int*   __restrict__ relations,
    const int*   __restrict__ tails,
    const unsigned int* __restrict__ eh,
    const float* __restrict__ rdot,
    float*       __restrict__ accp)      // [N_ITEM][HOPS][DIM]
{
    const int wave = (blockIdx.x * blockDim.x + threadIdx.x) >> 6;  // = h*N_ITEM + i
    const int lane = threadIdx.x & 63;
    if (wave >= HOPS * N_ITEM) return;
    const int h  = wave < N_ITEM ? 0 : 1;
    const int i  = wave - h * N_ITEM;
    const int g8 = lane >> 3;            // row-group within gather instr
    const int p8 = lane & 7;             // 16B slot within a 128B row

    const int base = wave * N_MEM;       // [H][N_ITEM][N_MEM] flat

    // --- index loads: lane's memory for step k is m = 8k + g8 ---
    int hk[4], tk[4], rk[4];
#pragma unroll
    for (int k = 0; k < 4; ++k) {
        hk[k] = heads[base + 8 * k + g8];
        tk[k] = tails[base + 8 * k + g8];
        rk[k] = relations[base + 8 * k + g8];
    }

    // --- fire all 8 row gathers (1 line-request per row) ---
    const uint4* __restrict__ E = (const uint4*)eh;
    uint4 hraw[4], traw[4];
#pragma unroll
    for (int k = 0; k < 4; ++k) hraw[k] = E[(size_t)hk[k] * 8 + p8];
#pragma unroll
    for (int k = 0; k < 4; ++k) traw[k] = E[(size_t)tk[k] * 8 + p8];

    // --- overlap: weight slices, rdot, bias ---
    const f4* __restrict__ W4 = (const f4*)W_w;
    const f4 wh0 = W4[p8 * 2],      wh1 = W4[p8 * 2 + 1];
    const f4 wt0 = W4[32 + p8 * 2], wt1 = W4[32 + p8 * 2 + 1];
    const float bias = W_b[0];
    float lr[4];
#pragma unroll
    for (int k = 0; k < 4; ++k) lr[k] = rdot[rk[k]];   // 128B table: L1

    // --- logits + softmax numerators ---
    float tef[4][8];
    float e[4];
    float se = 0.f;
#pragma unroll
    for (int k = 0; k < 4; ++k) {
        float hf[8];
        unpack8(hraw[k], hf);
        unpack8(traw[k], tef[k]);
        float v = hf[0] * wh0.x + hf[1] * wh0.y + hf[2] * wh0.z + hf[3] * wh0.w
                + hf[4] * wh1.x + hf[5] * wh1.y + hf[6] * wh1.z + hf[7] * wh1.w
                + tef[k][0] * wt0.x + tef[k][1] * wt0.y + tef[k][2] * wt0.z + tef[k][3] * wt0.w
                + tef[k][4] * wt1.x + tef[k][5] * wt1.y + tef[k][6] * wt1.z + tef[k][7] * wt1.w;
        v += __shfl_xor(v, 1, 64);
        v += __shfl_xor(v, 2, 64);
        v += __shfl_xor(v, 4, 64);
        const float logit = v + lr[k] + bias;
        const float sig   = 1.f / (1.f + __expf(-logit));
        e[k] = __expf(sig);
        se += e[k];
    }
    se += __shfl_xor(se, 8, 64);
    se += __shfl_xor(se, 16, 64);
    se += __shfl_xor(se, 32, 64);
    const float inv = 1.f / se;

    // --- weighted tail sum ---
    float acc8[8] = {0.f, 0.f, 0.f, 0.f, 0.f, 0.f, 0.f, 0.f};
#pragma unroll
    for (int k = 0; k < 4; ++k) {
        const float w = e[k] * inv;
#pragma unroll
        for (int j = 0; j < 8; ++j) acc8[j] += w * tef[k][j];
    }
#pragma unroll
    for (int j = 0; j < 8; ++j) {
        acc8[j] += __shfl_xor(acc8[j], 8, 64);
        acc8[j] += __shfl_xor(acc8[j], 16, 64);
        acc8[j] += __shfl_xor(acc8[j], 32, 64);
    }
    if (g8 == 0) {   // lane == p8: owns elements [8*p8, 8*p8+8)
        f4 s0 = {acc8[0], acc8[1], acc8[2], acc8[3]};
        f4 s1 = {acc8[4], acc8[5], acc8[6], acc8[7]};
        ((f4*)accp)[((size_t)i * 2 + h) * 16 + lane * 2]     = s0;
        ((f4*)accp)[((size_t)i * 2 + h) * 16 + lane * 2 + 1] = s1;
    }
}

// folded[i] = entity[item_ids[i]] + accp[i][0] + accp[i][1]  (fp32, exact)
__global__ __launch_bounds__(256) void ripple_fold(
    const float* __restrict__ entity_emb,
    const int*   __restrict__ item_ids,
    const float* __restrict__ accp,
    float*       __restrict__ folded)
{
    const int t = blockIdx.x * blockDim.x + threadIdx.x;
    if (t >= N_ITEM * 16) return;
    const int i = t >> 4;
    const int p = t & 15;
    const f4* __restrict__ E4 = (const f4*)entity_emb;
    const f4* __restrict__ A4 = (const f4*)accp;
    const f4 a  = A4[(size_t)i * 32 + p];
    const f4 b  = A4[(size_t)i * 32 + 16 + p];
    const f4 it = E4[(size_t)item_ids[i] * 16 + p];
    f4 r;
    r.x = it.x + a.x + b.x;
    r.y = it.y + a.y + b.y;
    r.z = it.z + a.z + b.z;
    r.w = it.w + a.w + b.w;
    ((f4*)folded)[(size_t)i * 16 + p] = r;
}

__global__ __launch_bounds__(256) void ripple_stage2(
    const float* __restrict__ entity_emb,
    const int*   __restrict__ records_idx,
    const int*   __restrict__ items,
    const float* __restrict__ folded,
    float*       __restrict__ out)
{
    const int wave = (blockIdx.x * blockDim.x + threadIdx.x) >> 6;
    const int lane = threadIdx.x & 63;
    if (wave >= BATCH) return;
    const int b = wave;
    const int g = lane >> 4;
    const int p = lane & 15;

    const f4* __restrict__ A4 = (const f4*)folded;
    const f4* __restrict__ E4 = (const f4*)entity_emb;

    const int rb = b * HIST;
    int idx[13];
    float wgt[13];
#pragma unroll
    for (int k = 0; k < 13; ++k) {
        const int j  = 4 * k + g;
        const int jc = j < HIST ? j : (HIST - 1);
        wgt[k] = j < HIST ? 1.f : 0.f;
        idx[k] = records_idx[rb + jc];
    }

    f4 user = {0.f, 0.f, 0.f, 0.f};
#pragma unroll
    for (int k = 0; k < 13; ++k) {
        const f4 r = A4[(size_t)idx[k] * 16 + p];
        user.x += wgt[k] * r.x;
        user.y += wgt[k] * r.y;
        user.z += wgt[k] * r.z;
        user.w += wgt[k] * r.w;
    }
    user.x += __shfl_xor(user.x, 16, 64);
    user.x += __shfl_xor(user.x, 32, 64);
    user.y += __shfl_xor(user.y, 16, 64);
    user.y += __shfl_xor(user.y, 32, 64);
    user.z += __shfl_xor(user.z, 16, 64);
    user.z += __shfl_xor(user.z, 32, 64);
    user.w += __shfl_xor(user.w, 16, 64);
    user.w += __shfl_xor(user.w, 32, 64);

    const f4 pair = E4[(size_t)items[b] * 16 + p];
    float dot = user.x * pair.x + user.y * pair.y + user.z * pair.z + user.w * pair.w;
    dot += __shfl_xor(dot, 1, 64);
    dot += __shfl_xor(dot, 2, 64);
    dot += __shfl_xor(dot, 4, 64);
    dot += __shfl_xor(dot, 8, 64);
    if (lane == 0) out[b] = 1.f / (1.f + __expf(-dot));
}

extern "C" void kernel_launch(void* const* d_in, const int* in_sizes, int n_in,
                              void* d_out, int out_size, void* d_ws, size_t ws_size,
                              hipStream_t stream) {
    const float* entity_emb   = (const float*)d_in[0];
    const float* relation_emb = (const float*)d_in[1];
    const float* W_w          = (const float*)d_in[2];
    const float* W_b          = (const float*)d_in[3];
    const int*   item_ids     = (const int*)d_in[4];
    const int*   heads        = (const int*)d_in[5];
    const int*   relations    = (const int*)d_in[6];
    const int*   tails        = (const int*)d_in[7];
    const int*   records_idx  = (const int*)d_in[8];
    const int*   items        = (const int*)d_in[9];
    float* out = (float*)d_out;

    unsigned int* eh   = (unsigned int*)d_ws;                 // 64 MB (fp16 table)
    float* rdot        = (float*)(eh + (size_t)N_ENTITY * 32);// 128 B
    float* accp        = rdot + N_REL;                        // 5.12 MB
    float* folded      = accp + (size_t)N_ITEM * HOPS * DIM;  // 2.56 MB

    // Pass 0: fp16 conversion + rdot (streaming, coalesced).
    const int rowsC   = N_ENTITY + N_REL;
    const int wavesC  = (rowsC + 3) / 4;
    const int blocksC = (wavesC + 3) / 4;
    ripple_convert<<<blocksC, 256, 0, stream>>>(entity_emb, relation_emb, W_w,
                                                eh, rdot);

    const int waves1  = HOPS * N_ITEM;
    const int blocks1 = (waves1 + 3) / 4;
    ripple_stage1<<<blocks1, 256, 0, stream>>>(W_w, W_b, heads, relations, tails,
                                               eh, rdot, accp);

    const int blocksF = (N_ITEM * 16 + 255) / 256;
    ripple_fold<<<blocksF, 256, 0, stream>>>(entity_emb, item_ids, accp, folded);

    const int blocks2 = (BATCH + 3) / 4;
    ripple_stage2<<<blocks2, 256, 0, stream>>>(entity_emb, records_idx, items,
                                               folded, out);
}

// Round 9
// 228.230 us; speedup vs baseline: 1.0597x; 1.0597x over previous
//
#include <hip/hip_runtime.h>
#include <math.h>

#define DIM      64
#define N_MEM    32
#define N_ENTITY 500000
#define N_REL    32
#define N_ITEM   10000
#define HOPS     2
#define BATCH    4096
#define HIST     50

typedef float4 f4;

// ---------------------------------------------------------------------------
// Tiny pass: rdot[r] = dot(relation[r], w_r) for 32 relations. ~2us.
// Removes 1.28M relation-row line-addresses from stage1.
// ---------------------------------------------------------------------------
__global__ __launch_bounds__(256) void ripple_rdot(
    const float* __restrict__ relation_emb,
    const float* __restrict__ W_w,
    float* __restrict__ rdot)           // [N_REL]
{
    const int wave = (blockIdx.x * blockDim.x + threadIdx.x) >> 6;
    const int lane = threadIdx.x & 63;
    const int g = lane >> 4;
    const int p = lane & 15;
    const int r = wave * 4 + g;
    if (r >= N_REL) return;
    const f4 wr = ((const f4*)W_w)[16 + p];
    const f4 r4 = ((const f4*)relation_emb)[(size_t)r * 16 + p];
    float vr = r4.x * wr.x + r4.y * wr.y + r4.z * wr.z + r4.w * wr.w;
    vr += __shfl_xor(vr, 1, 64);
    vr += __shfl_xor(vr, 2, 64);
    vr += __shfl_xor(vr, 4, 64);
    vr += __shfl_xor(vr, 8, 64);
    if (p == 0) rdot[r] = vr;
}

// ---------------------------------------------------------------------------
// Stage 1 (R5 structure): one wave per (item, hop); lane = g*16+p; per wave
// 8 head + 8 tail f4 row-gathers all in flight; relation logit from rdot[].
// ---------------------------------------------------------------------------
__global__ __launch_bounds__(256) void ripple_stage1(
    const float* __restrict__ W_w,
    const float* __restrict__ W_b,
    const int*   __restrict__ heads,
    const int*   __restrict__ relations,
    const int*   __restrict__ tails,
    const float* __restrict__ entity_emb,
    const float* __restrict__ rdot,
    float*       __restrict__ accp)      // [N_ITEM][HOPS][DIM]
{
    const int wave = (blockIdx.x * blockDim.x + threadIdx.x) >> 6;  // = h*N_ITEM + i
    const int lane = threadIdx.x & 63;
    if (wave >= HOPS * N_ITEM) return;
    const int h = wave < N_ITEM ? 0 : 1;
    const int i = wave - h * N_ITEM;
    const int g = lane >> 4;
    const int p = lane & 15;

    const f4* __restrict__ E4 = (const f4*)entity_emb;
    const f4* __restrict__ W4 = (const f4*)W_w;

    const f4 wh = W4[p];
    const f4 wt = W4[32 + p];
    const float bias = W_b[0];

    const int base = wave * N_MEM + g;   // this lane's m = 4k+g

    // ---- Phase 0: indices ----
    int hi[8], ri[8], ti[8];
#pragma unroll
    for (int k = 0; k < 8; ++k) {
        hi[k] = heads[base + 4 * k];
        ri[k] = relations[base + 4 * k];
        ti[k] = tails[base + 4 * k];
    }

    // ---- Phase A: 16 f4 row-gathers in flight (head + tail) ----
    f4 he[8], te[8];
#pragma unroll
    for (int k = 0; k < 8; ++k) he[k] = E4[(size_t)hi[k] * 16 + p];
#pragma unroll
    for (int k = 0; k < 8; ++k) te[k] = E4[(size_t)ti[k] * 16 + p];

    // relation logits: 4B loads from 128B L1-resident table
    float lr[8];
#pragma unroll
    for (int k = 0; k < 8; ++k) lr[k] = rdot[ri[k]];

    float part[8];
#pragma unroll
    for (int k = 0; k < 8; ++k) {
        part[k] = he[k].x * wh.x + he[k].y * wh.y + he[k].z * wh.z + he[k].w * wh.w
                + te[k].x * wt.x + te[k].y * wt.y + te[k].z * wt.z + te[k].w * wt.w;
    }

    // ---- Phase B: 16-lane reduces (4 memories in parallel), sigmoid+exp ----
    float e[8];
    float se = 0.f;
#pragma unroll
    for (int k = 0; k < 8; ++k) {
        float v = part[k];
        v += __shfl_xor(v, 1, 64);
        v += __shfl_xor(v, 2, 64);
        v += __shfl_xor(v, 4, 64);
        v += __shfl_xor(v, 8, 64);
        const float logit = v + lr[k] + bias;
        const float sig   = 1.f / (1.f + __expf(-logit));
        const float ex    = __expf(sig);
        e[k] = ex;
        se += ex;
    }
    se += __shfl_xor(se, 16, 64);
    se += __shfl_xor(se, 32, 64);
    const float inv = 1.f / se;

    // ---- Phase C: weighted tail sum from registers ----
    f4 acc = {0.f, 0.f, 0.f, 0.f};
#pragma unroll
    for (int k = 0; k < 8; ++k) {
        const float w = e[k] * inv;
        acc.x += w * te[k].x;
        acc.y += w * te[k].y;
        acc.z += w * te[k].z;
        acc.w += w * te[k].w;
    }

    acc.x += __shfl_xor(acc.x, 16, 64);
    acc.x += __shfl_xor(acc.x, 32, 64);
    acc.y += __shfl_xor(acc.y, 16, 64);
    acc.y += __shfl_xor(acc.y, 32, 64);
    acc.z += __shfl_xor(acc.z, 16, 64);
    acc.z += __shfl_xor(acc.z, 32, 64);
    acc.w += __shfl_xor(acc.w, 16, 64);
    acc.w += __shfl_xor(acc.w, 32, 64);
    if (g == 0) ((f4*)accp)[((size_t)i * 2 + h) * 16 + p] = acc;
}

// folded[i] = entity[item_ids[i]] + accp[i][0] + accp[i][1]
__global__ __launch_bounds__(256) void ripple_fold(
    const float* __restrict__ entity_emb,
    const int*   __restrict__ item_ids,
    const float* __restrict__ accp,
    float*       __restrict__ folded)
{
    const int t = blockIdx.x * blockDim.x + threadIdx.x;
    if (t >= N_ITEM * 16) return;
    const int i = t >> 4;
    const int p = t & 15;
    const f4* __restrict__ E4 = (const f4*)entity_emb;
    const f4* __restrict__ A4 = (const f4*)accp;
    const f4 a  = A4[(size_t)i * 32 + p];
    const f4 b  = A4[(size_t)i * 32 + 16 + p];
    const f4 it = E4[(size_t)item_ids[i] * 16 + p];
    f4 r;
    r.x = it.x + a.x + b.x;
    r.y = it.y + a.y + b.y;
    r.z = it.z + a.z + b.z;
    r.w = it.w + a.w + b.w;
    ((f4*)folded)[(size_t)i * 16 + p] = r;
}

__global__ __launch_bounds__(256) void ripple_stage2(
    const float* __restrict__ entity_emb,
    const int*   __restrict__ records_idx,
    const int*   __restrict__ items,
    const float* __restrict__ folded,
    float*       __restrict__ out)
{
    const int wave = (blockIdx.x * blockDim.x + threadIdx.x) >> 6;
    const int lane = threadIdx.x & 63;
    if (wave >= BATCH) return;
    const int b = wave;
    const int g = lane >> 4;
    const int p = lane & 15;

    const f4* __restrict__ A4 = (const f4*)folded;
    const f4* __restrict__ E4 = (const f4*)entity_emb;

    const int rb = b * HIST;
    int idx[13];
    float wgt[13];
#pragma unroll
    for (int k = 0; k < 13; ++k) {
        const int j  = 4 * k + g;
        const int jc = j < HIST ? j : (HIST - 1);
        wgt[k] = j < HIST ? 1.f : 0.f;
        idx[k] = records_idx[rb + jc];
    }

    f4 user = {0.f, 0.f, 0.f, 0.f};
#pragma unroll
    for (int k = 0; k < 13; ++k) {
        const f4 r = A4[(size_t)idx[k] * 16 + p];
        user.x += wgt[k] * r.x;
        user.y += wgt[k] * r.y;
        user.z += wgt[k] * r.z;
        user.w += wgt[k] * r.w;
    }
    user.x += __shfl_xor(user.x, 16, 64);
    user.x += __shfl_xor(user.x, 32, 64);
    user.y += __shfl_xor(user.y, 16, 64);
    user.y += __shfl_xor(user.y, 32, 64);
    user.z += __shfl_xor(user.z, 16, 64);
    user.z += __shfl_xor(user.z, 32, 64);
    user.w += __shfl_xor(user.w, 16, 64);
    user.w += __shfl_xor(user.w, 32, 64);

    const f4 pair = E4[(size_t)items[b] * 16 + p];
    float dot = user.x * pair.x + user.y * pair.y + user.z * pair.z + user.w * pair.w;
    dot += __shfl_xor(dot, 1, 64);
    dot += __shfl_xor(dot, 2, 64);
    dot += __shfl_xor(dot, 4, 64);
    dot += __shfl_xor(dot, 8, 64);
    if (lane == 0) out[b] = 1.f / (1.f + __expf(-dot));
}

extern "C" void kernel_launch(void* const* d_in, const int* in_sizes, int n_in,
                              void* d_out, int out_size, void* d_ws, size_t ws_size,
                              hipStream_t stream) {
    const float* entity_emb   = (const float*)d_in[0];
    const float* relation_emb = (const float*)d_in[1];
    const float* W_w          = (const float*)d_in[2];
    const float* W_b          = (const float*)d_in[3];
    const int*   item_ids     = (const int*)d_in[4];
    const int*   heads        = (const int*)d_in[5];
    const int*   relations    = (const int*)d_in[6];
    const int*   tails        = (const int*)d_in[7];
    const int*   records_idx  = (const int*)d_in[8];
    const int*   items        = (const int*)d_in[9];
    float* out = (float*)d_out;

    float* rdot   = (float*)d_ws;                          // 128 B
    float* accp   = rdot + N_REL;                          // 5.12 MB
    float* folded = accp + (size_t)N_ITEM * HOPS * DIM;    // 2.56 MB

    ripple_rdot<<<2, 256, 0, stream>>>(relation_emb, W_w, rdot);

    const int waves1  = HOPS * N_ITEM;          // 20000 waves, 4 per block
    const int blocks1 = (waves1 + 3) / 4;
    ripple_stage1<<<blocks1, 256, 0, stream>>>(W_w, W_b, heads, relations, tails,
                                               entity_emb, rdot, accp);

    const int blocksF = (N_ITEM * 16 + 255) / 256;
    ripple_fold<<<blocksF, 256, 0, stream>>>(entity_emb, item_ids, accp, folded);

    const int blocks2 = (BATCH + 3) / 4;
    ripple_stage2<<<blocks2, 256, 0, stream>>>(entity_emb, records_idx, items,
                                               folded, out);
}